// Round 16
// baseline (1577.769 us; speedup 1.0000x reference)
//
#include <hip/hip_runtime.h>
#include <hip/hip_fp16.h>
#include <cstdint>
#include <cstddef>

// OwnVanillaRNN R16: 1-wave/SIMD fat threads (T=256), 512-reg budget.
// R15 lesson: no direct-AGPR VALU operands on gfx950 -> AGPR use costs a
// v_accvgpr_read. Fix the RATIO instead: waves_per_eu(1,1) + T=256 gives
// each thread 256 arch + 256 acc regs. Thread = (16 rows x 72-dim slice):
// 144 frags = 113 named-SSA (compiler splits arch/AGPR itself, a127 unlock,
// R12-proven) + 31 LDS. DS issues/CU/step drop 224 -> 160 and only 4 waves
// contend for the LDS unit. Same DPP 8-lane K-reduce; 2 rows written/lane.

constexpr int BATCH = 256;
constexpr int SEQ   = 512;
constexpr int IN    = 64;
constexpr int HID   = 512;
constexpr int OUT   = 64;
constexpr int T     = 256;        // threads (4 waves, 1 per SIMD)
constexpr int DTOT  = HID + IN;   // 576
constexpr int DSL   = DTOT / 8;   // 72 dims per slice
constexpr int NF    = 144;        // frags per thread (16 rows x 9 groups)
constexpr int NSSA  = 113;        // named-SSA frags (k = 0..112)
constexpr int NL    = 31;         // LDS frags (k = 113..143)

typedef _Float16 half2v __attribute__((ext_vector_type(2)));

__device__ __forceinline__ float fdot2(uint32_t w, uint32_t h, float acc) {
    return __builtin_amdgcn_fdot2(__builtin_bit_cast(half2v, w),
                                  __builtin_bit_cast(half2v, h), acc, false);
}
__device__ __forceinline__ uint32_t packh2(float lo, float hi) {
    return (uint32_t)__half_as_ushort(__float2half(lo)) |
           ((uint32_t)__half_as_ushort(__float2half(hi)) << 16);
}
// DPP add: 0xB1 quad xor1, 0x4E quad xor2, 0x141 ROW_HALF_MIRROR.
// Symmetric -> full 8-lane-group sum in EVERY lane (R11/R12-verified).
template <int CTRL>
__device__ __forceinline__ float dpp_add(float v) {
    int i = __builtin_bit_cast(int, v);
    int p = __builtin_amdgcn_update_dpp(i, i, CTRL, 0xF, 0xF, false);
    return v + __builtin_bit_cast(float, p);
}

// Frag k (0..143): p = k>>4 (h-position group), r = k&15 (row in 16-row set).
// Thread t: g = t>>3, s = t&7. Weight = W~[16g+r][72s+8p .. +7] f16,
// W~[o] = [Wh[o] ; Wx[o]]. d0 = 72s+8p is 8-aligned (no boundary straddle).
__global__ __launch_bounds__(256, 1)
void prep_w(const float* __restrict__ Wh, const float* __restrict__ Wx,
            uint4* __restrict__ Wpk) {
    const int idx = blockIdx.x * 256 + threadIdx.x;   // 144*256
    const int k = idx >> 8, t = idx & (T - 1);
    const int p = k >> 4, r = k & 15;
    const int g = t >> 3, s = t & 7;
    const int o = 16 * g + r;
    const int d0 = DSL * s + 8 * p;
    const float* src = (d0 < HID) ? (Wh + (size_t)o * HID + d0)
                                  : (Wx + (size_t)o * IN + (d0 - HID));
    uint4 d;
    d.x = packh2(src[0], src[1]);
    d.y = packh2(src[2], src[3]);
    d.z = packh2(src[4], src[5]);
    d.w = packh2(src[6], src[7]);
    Wpk[idx] = d;
}

// 113 named-SSA weight frags.
#define RG_LIST(M) \
  M(0)   M(1)   M(2)   M(3)   M(4)   M(5)   M(6)   M(7)   M(8)   M(9)  \
  M(10)  M(11)  M(12)  M(13)  M(14)  M(15)  M(16)  M(17)  M(18)  M(19) \
  M(20)  M(21)  M(22)  M(23)  M(24)  M(25)  M(26)  M(27)  M(28)  M(29) \
  M(30)  M(31)  M(32)  M(33)  M(34)  M(35)  M(36)  M(37)  M(38)  M(39) \
  M(40)  M(41)  M(42)  M(43)  M(44)  M(45)  M(46)  M(47)  M(48)  M(49) \
  M(50)  M(51)  M(52)  M(53)  M(54)  M(55)  M(56)  M(57)  M(58)  M(59) \
  M(60)  M(61)  M(62)  M(63)  M(64)  M(65)  M(66)  M(67)  M(68)  M(69) \
  M(70)  M(71)  M(72)  M(73)  M(74)  M(75)  M(76)  M(77)  M(78)  M(79) \
  M(80)  M(81)  M(82)  M(83)  M(84)  M(85)  M(86)  M(87)  M(88)  M(89) \
  M(90)  M(91)  M(92)  M(93)  M(94)  M(95)  M(96)  M(97)  M(98)  M(99) \
  M(100) M(101) M(102) M(103) M(104) M(105) M(106) M(107) M(108) M(109) \
  M(110) M(111) M(112)

// MAC helpers; hv must be in scope. Param Z: no x/y/z/w collision (R9).
#define MV(f, Z) { \
    Z = fdot2(w##f.x, hv.x, Z); Z = fdot2(w##f.y, hv.y, Z); \
    Z = fdot2(w##f.z, hv.z, Z); Z = fdot2(w##f.w, hv.w, Z); }
#define ML(i, Z) { const uint4 wv = wl[t * NL + (i)]; \
    Z = fdot2(wv.x, hv.x, Z); Z = fdot2(wv.y, hv.y, Z); \
    Z = fdot2(wv.z, hv.z, Z); Z = fdot2(wv.w, hv.w, Z); }

__global__ __launch_bounds__(T, 1)
__attribute__((amdgpu_waves_per_eu(1, 1)))
void rnn_main(const float* __restrict__ x,  const float* __restrict__ bx,
              const float* __restrict__ bh, const float* __restrict__ Wy,
              const float* __restrict__ by, const uint4* __restrict__ Wpk,
              float* __restrict__ y) {
    __shared__ uint4 wl[T * NL];                     // 124 KB, thread-major
    __shared__ __align__(16) __half hb2[2][DTOT];    // double-buffered h~

    const int b = blockIdx.x, t = threadIdx.x;
    const int s = t & 7;

    // AGPR unlock (R12-proven): keep the AGPR class live so the allocator
    // spills weight overflow to AGPRs, not scratch.
    {
        uint32_t agk;
        asm volatile("v_accvgpr_write_b32 a255, 0\n\t"
                     "s_nop 1\n\t"
                     "v_accvgpr_read_b32 %0, a255" : "=v"(agk));
        if (agk == 0xDEADBEEFu) hb2[0][0] = __float2half(0.0f);  // never
    }

    // ---- one-time: LDS weights. Stride 31 uint4 = 124 dw == 28 mod 32:
    // 8 consecutive lanes hit disjoint 4-bank windows -> conflict-free. ----
    #pragma unroll
    for (int i = 0; i < NL; ++i)
        wl[t * NL + i] = Wpk[(size_t)(NSSA + i) * T + t];

    // ---- one-time: 113 frags as plain named SSA; allocator splits
    // arch/AGPR itself (R12 lesson: never hand-write accvgpr asm). ----
#define DECL_WV(f) const uint4 w##f = Wpk[(size_t)(f) * T + t];
    RG_LIST(DECL_WV)
#undef DECL_WV

    // Biases for the 2 rows this lane writes (rows 2t, 2t+1).
    const float bs0 = bx[2 * t]     + bh[2 * t];
    const float bs1 = bx[2 * t + 1] + bh[2 * t + 1];
    const float* xb = x + (size_t)b * SEQ * IN;

    ((uint32_t*)hb2[0])[t] = 0u;                        // h0 = 0 (2 halves/thread)
    if (t < IN) hb2[0][HID + t] = __float2half(xb[t]);  // x_0
    float xv = (t < IN) ? xb[IN + t] : 0.0f;            // x_1 prefetched
    __syncthreads();

    #pragma unroll 1
    for (int tt = 0; tt < SEQ; ++tt) {
        const int c = tt & 1;
        const uint4* hb = (const uint4*)(&hb2[c][0] + DSL * s);
        float z0  = 0.f, z1  = 0.f, z2  = 0.f, z3  = 0.f;
        float z4  = 0.f, z5  = 0.f, z6  = 0.f, z7  = 0.f;
        float z8  = 0.f, z9  = 0.f, z10 = 0.f, z11 = 0.f;
        float z12 = 0.f, z13 = 0.f, z14 = 0.f, z15 = 0.f;

        { const uint4 hv = hb[0];   // k 0..15
          MV(0,z0)   MV(1,z1)   MV(2,z2)   MV(3,z3)   MV(4,z4)   MV(5,z5)
          MV(6,z6)   MV(7,z7)   MV(8,z8)   MV(9,z9)   MV(10,z10) MV(11,z11)
          MV(12,z12) MV(13,z13) MV(14,z14) MV(15,z15) }
        { const uint4 hv = hb[1];   // k 16..31
          MV(16,z0)  MV(17,z1)  MV(18,z2)  MV(19,z3)  MV(20,z4)  MV(21,z5)
          MV(22,z6)  MV(23,z7)  MV(24,z8)  MV(25,z9)  MV(26,z10) MV(27,z11)
          MV(28,z12) MV(29,z13) MV(30,z14) MV(31,z15) }
        { const uint4 hv = hb[2];   // k 32..47
          MV(32,z0)  MV(33,z1)  MV(34,z2)  MV(35,z3)  MV(36,z4)  MV(37,z5)
          MV(38,z6)  MV(39,z7)  MV(40,z8)  MV(41,z9)  MV(42,z10) MV(43,z11)
          MV(44,z12) MV(45,z13) MV(46,z14) MV(47,z15) }
        { const uint4 hv = hb[3];   // k 48..63
          MV(48,z0)  MV(49,z1)  MV(50,z2)  MV(51,z3)  MV(52,z4)  MV(53,z5)
          MV(54,z6)  MV(55,z7)  MV(56,z8)  MV(57,z9)  MV(58,z10) MV(59,z11)
          MV(60,z12) MV(61,z13) MV(62,z14) MV(63,z15) }
        { const uint4 hv = hb[4];   // k 64..79
          MV(64,z0)  MV(65,z1)  MV(66,z2)  MV(67,z3)  MV(68,z4)  MV(69,z5)
          MV(70,z6)  MV(71,z7)  MV(72,z8)  MV(73,z9)  MV(74,z10) MV(75,z11)
          MV(76,z12) MV(77,z13) MV(78,z14) MV(79,z15) }
        { const uint4 hv = hb[5];   // k 80..95
          MV(80,z0)  MV(81,z1)  MV(82,z2)  MV(83,z3)  MV(84,z4)  MV(85,z5)
          MV(86,z6)  MV(87,z7)  MV(88,z8)  MV(89,z9)  MV(90,z10) MV(91,z11)
          MV(92,z12) MV(93,z13) MV(94,z14) MV(95,z15) }
        { const uint4 hv = hb[6];   // k 96..111
          MV(96,z0)  MV(97,z1)  MV(98,z2)  MV(99,z3)  MV(100,z4) MV(101,z5)
          MV(102,z6) MV(103,z7) MV(104,z8) MV(105,z9) MV(106,z10) MV(107,z11)
          MV(108,z12) MV(109,z13) MV(110,z14) MV(111,z15) }
        { const uint4 hv = hb[7];   // k 112 (SSA) + 113..127 (LDS 0..14)
          MV(112,z0) ML(0,z1)   ML(1,z2)   ML(2,z3)   ML(3,z4)   ML(4,z5)
          ML(5,z6)   ML(6,z7)   ML(7,z8)   ML(8,z9)   ML(9,z10)  ML(10,z11)
          ML(11,z12) ML(12,z13) ML(13,z14) ML(14,z15) }
        { const uint4 hv = hb[8];   // k 128..143 (LDS 15..30)
          ML(15,z0)  ML(16,z1)  ML(17,z2)  ML(18,z3)  ML(19,z4)  ML(20,z5)
          ML(21,z6)  ML(22,z7)  ML(23,z8)  ML(24,z9)  ML(25,z10) ML(26,z11)
          ML(27,z12) ML(28,z13) ML(29,z14) ML(30,z15) }

        // 8-way K-reduce per z (R11-verified symmetric stages).
        z0  = dpp_add<0xB1>(z0);  z0  = dpp_add<0x4E>(z0);  z0  = dpp_add<0x141>(z0);
        z1  = dpp_add<0xB1>(z1);  z1  = dpp_add<0x4E>(z1);  z1  = dpp_add<0x141>(z1);
        z2  = dpp_add<0xB1>(z2);  z2  = dpp_add<0x4E>(z2);  z2  = dpp_add<0x141>(z2);
        z3  = dpp_add<0xB1>(z3);  z3  = dpp_add<0x4E>(z3);  z3  = dpp_add<0x141>(z3);
        z4  = dpp_add<0xB1>(z4);  z4  = dpp_add<0x4E>(z4);  z4  = dpp_add<0x141>(z4);
        z5  = dpp_add<0xB1>(z5);  z5  = dpp_add<0x4E>(z5);  z5  = dpp_add<0x141>(z5);
        z6  = dpp_add<0xB1>(z6);  z6  = dpp_add<0x4E>(z6);  z6  = dpp_add<0x141>(z6);
        z7  = dpp_add<0xB1>(z7);  z7  = dpp_add<0x4E>(z7);  z7  = dpp_add<0x141>(z7);
        z8  = dpp_add<0xB1>(z8);  z8  = dpp_add<0x4E>(z8);  z8  = dpp_add<0x141>(z8);
        z9  = dpp_add<0xB1>(z9);  z9  = dpp_add<0x4E>(z9);  z9  = dpp_add<0x141>(z9);
        z10 = dpp_add<0xB1>(z10); z10 = dpp_add<0x4E>(z10); z10 = dpp_add<0x141>(z10);
        z11 = dpp_add<0xB1>(z11); z11 = dpp_add<0x4E>(z11); z11 = dpp_add<0x141>(z11);
        z12 = dpp_add<0xB1>(z12); z12 = dpp_add<0x4E>(z12); z12 = dpp_add<0x141>(z12);
        z13 = dpp_add<0xB1>(z13); z13 = dpp_add<0x4E>(z13); z13 = dpp_add<0x141>(z13);
        z14 = dpp_add<0xB1>(z14); z14 = dpp_add<0x4E>(z14); z14 = dpp_add<0x141>(z14);
        z15 = dpp_add<0xB1>(z15); z15 = dpp_add<0x4E>(z15); z15 = dpp_add<0x141>(z15);

        // Lane s writes rows 16g+2s (=2t) and 16g+2s+1 (=2t+1):
        // select z_{2s} (even set) and z_{2s+1} (odd set) via 3-bit trees.
        const float ea = (s & 1) ? z2  : z0;
        const float eb = (s & 1) ? z6  : z4;
        const float ec = (s & 1) ? z10 : z8;
        const float ed = (s & 1) ? z14 : z12;
        const float ee = (s & 2) ? eb  : ea;
        const float ef = (s & 2) ? ed  : ec;
        const float zE = (s & 4) ? ef  : ee;          // z_{2s}
        const float oa = (s & 1) ? z3  : z1;
        const float ob = (s & 1) ? z7  : z5;
        const float oc = (s & 1) ? z11 : z9;
        const float od = (s & 1) ? z15 : z13;
        const float oe = (s & 2) ? ob  : oa;
        const float of_ = (s & 2) ? od : oc;
        const float zO = (s & 4) ? of_ : oe;          // z_{2s+1}

        const float h0 = 1.f - 2.f * __builtin_amdgcn_rcpf(__expf(2.f * (zE + bs0)) + 1.f);
        const float h1 = 1.f - 2.f * __builtin_amdgcn_rcpf(__expf(2.f * (zO + bs1)) + 1.f);
        ((uint32_t*)hb2[c ^ 1])[t] = packh2(h0, h1);  // rows 2t, 2t+1

        if (t < IN) {
            hb2[c ^ 1][HID + t] = __float2half(xv);   // x_{tt+1}
            if (tt + 2 < SEQ) xv = xb[(size_t)(tt + 2) * IN + t];
        }
        __syncthreads();
    }

    // ---- epilogue: y = h_T @ Wy^T + by (final h in buffer 0) ----
    if (t < OUT) {
        float acc = by[t];
        const float* wy = Wy + (size_t)t * HID;
        #pragma unroll 8
        for (int j = 0; j < HID; ++j)
            acc = fmaf(wy[j], __half2float(hb2[0][j]), acc);
        y[(size_t)b * OUT + t] = acc;
    }
}

extern "C" void kernel_launch(void* const* d_in, const int* in_sizes, int n_in,
                              void* d_out, int out_size, void* d_ws, size_t ws_size,
                              hipStream_t stream) {
    const float* x  = (const float*)d_in[0];
    const float* Wx = (const float*)d_in[1];
    const float* bx = (const float*)d_in[2];
    const float* Wh = (const float*)d_in[3];
    const float* bh = (const float*)d_in[4];
    const float* Wy = (const float*)d_in[5];
    const float* by = (const float*)d_in[6];
    float* y = (float*)d_out;

    uint4* Wpk = (uint4*)d_ws;  // 144*256*16 B = 576 KB packed f16 fragments

    hipLaunchKernelGGL(prep_w, dim3(NF * T / 256), dim3(256), 0, stream,
                       Wh, Wx, Wpk);
    hipLaunchKernelGGL(rnn_main, dim3(BATCH), dim3(T), 0, stream,
                       x, bx, bh, Wy, by, Wpk, y);
}